// Round 1
// baseline (513.191 us; speedup 1.0000x reference)
//
#include <hip/hip_runtime.h>
#include <hip/hip_fp16.h>
#include <math.h>

// ---------------- problem constants ----------------
// x: (16, 2048, 64) f32  -> out: (16, 2048, 64, 5) f32
// scales = {1,27,76,167,336}; morlet int_psi, n=1024, [-8,8]
#define NB    16
#define T     2048
#define NC    64
#define NROWS (NB*NC)     // 1024
#define PADL  2689        // 8*336+1
#define LW    7432        // padded row length (floats): 2689+2048+2689=7426 -> 7432
#define TAPS_STRIDE 5504  // int2 slots per scale (max dense 16*336+2=5378)

// ws layout (bytes):
//   0        : int counts[5]
//   64       : int2 taps[5][TAPS_STRIDE]            (220,160 B)
//   1<<20    : __half xT[1024][2048]                (4 MB)
//   5<<20    : __half outT[1024][5][2048]           (20 MB)   total = 25 MB
#define WS_TAPS  64
#define WS_XT    (1u<<20)
#define WS_OUTT  (5u<<20)

// ---------------- kernel 1: tap generation ----------------
// Mirrors pywt/reference float64 arithmetic EXACTLY for positions:
//   t = linspace(-8,8,1024); step = t[1]-t[0]  (note: (-8+16/1023)+8 roundtrip!)
//   j_i = int64(i / (scale*step)); k[i]=float32(int_psi[j_i])
// Derivative kernel: g[i] = sqrt(s)*(k[i]-k[i-1]), k[-1]=k[L]=0, i in [0,L], L=16s+1
// out[t] = sum_i g[i]*x[t-8s-1+i].  For s>=64 j increments by <=1 -> sparse slots=j.
__global__ __launch_bounds__(1024) void cwt_init_taps(int2* __restrict__ taps,
                                                      int* __restrict__ counts) {
    __shared__ double ps[1024];
    __shared__ double sc[1024];
    __shared__ float  k32[1024];
    const int tid = threadIdx.x;

    const double delta = 16.0 / 1023.0;
    double t = (tid == 1023) ? 8.0 : (-8.0 + delta * (double)tid);
    ps[tid] = exp(-0.5 * t * t) * cos(5.0 * t);
    __syncthreads();

    // inclusive scan (Hillis-Steele ping-pong); reassociation vs np.cumsum is ~1e-15, irrelevant
    double* a = ps; double* b = sc;
    for (int off = 1; off < 1024; off <<= 1) {
        double v = a[tid];
        if (tid >= off) v += a[tid - off];
        b[tid] = v;
        __syncthreads();
        double* tmp = a; a = b; b = tmp;
    }
    const double step = ((-8.0 + delta) + 8.0);   // reference: t[1]-t[0], NOT exactly 16/1023
    k32[tid] = (float)(a[tid] * step);
    __syncthreads();

    constexpr int SC[5] = {1, 27, 76, 167, 336};
    for (int sl = 0; sl < 5; ++sl) {
        const int s = SC[sl];
        const int L = 16 * s + 1;
        const double c = (double)s * step;
        const float sq = (float)sqrt((double)s);
        const bool dense = (s < 64);              // s=1,27: j always jumps -> all taps nonzero
        int2* base = taps + sl * TAPS_STRIDE;
        const int posoff = PADL - 8 * s - 1;      // fold conv offset into stored position
        for (int i = tid; i <= L; i += 1024) {
            if (i == 0) {
                base[0] = make_int2(posoff, __float_as_int(sq * k32[0]));
            } else if (i == L) {
                long long jl = (long long)((double)(L - 1) / c);
                if (jl > 1023) jl = 1023;
                const int slot = dense ? i : (int)(jl + 1);
                base[slot] = make_int2(L + posoff, __float_as_int(-sq * k32[jl]));
                counts[sl] = slot + 1;
            } else {
                long long j1 = (long long)((double)i / c);
                long long j0 = (long long)((double)(i - 1) / c);
                if (j1 > 1023) j1 = 1023;
                if (j0 > 1023) j0 = 1023;
                if (dense || j1 > j0) {
                    const int slot = dense ? i : (int)j1;
                    base[slot] = make_int2(i + posoff,
                                           __float_as_int(sq * (k32[j1] - k32[j0])));
                }
            }
        }
    }
}

// ---------------- kernel 2: transpose x(n,t,c) -> xT[(n*64+c)][t] as fp16 ----------------
__global__ __launch_bounds__(256) void cwt_transpose(const float* __restrict__ x,
                                                     __half* __restrict__ xT) {
    __shared__ float tile[64 * 65];               // +1 pad breaks bank conflicts on col read
    const int b  = blockIdx.x;                    // 0..511
    const int n  = b >> 5;
    const int t0 = (b & 31) << 6;
    const int tid = threadIdx.x;

    const float4* src = (const float4*)(x + ((size_t)(n * T + t0)) * NC);
    #pragma unroll
    for (int k = 0; k < 4; ++k) {
        float4 v = src[tid + 256 * k];
        const int flat = (tid + 256 * k) * 4;     // 0..4095 over (tt, c)
        const int tt = flat >> 6, c = flat & 63;
        tile[tt * 65 + c + 0] = v.x;
        tile[tt * 65 + c + 1] = v.y;
        tile[tt * 65 + c + 2] = v.z;
        tile[tt * 65 + c + 3] = v.w;
    }
    __syncthreads();
    const int lane = tid & 63, w = tid >> 6;
    for (int cc = w; cc < 64; cc += 4) {
        xT[((size_t)(n * 64 + cc)) * T + t0 + lane] = __float2half(tile[lane * 65 + cc]);
    }
}

// ---------------- kernel 3: per-row sparse conv (baseline, LDS-bound) ----------------
__global__ __launch_bounds__(256) void cwt_conv(const __half* __restrict__ xT,
                                                const int2* __restrict__ taps,
                                                const int*  __restrict__ counts,
                                                __half* __restrict__ outT) {
    __shared__ float xs[LW];
    const int row = blockIdx.x;
    const int tid = threadIdx.x;

    for (int i = tid; i < PADL; i += 256) xs[i] = 0.f;
    for (int i = PADL + T + tid; i < LW; i += 256) xs[i] = 0.f;
    const uint4* src = (const uint4*)(xT + (size_t)row * T);   // 8 halves/thread
    uint4 v = src[tid];
    const __half* hv = (const __half*)&v;
    #pragma unroll
    for (int r = 0; r < 8; ++r) xs[PADL + tid * 8 + r] = __half2float(hv[r]);
    __syncthreads();

    for (int sl = 0; sl < 5; ++sl) {
        const int cnt = counts[sl];                // uniform -> s_load
        const int2* tp = taps + sl * TAPS_STRIDE;
        float acc[8];
        #pragma unroll
        for (int r = 0; r < 8; ++r) acc[r] = 0.f;
        for (int j = 0; j < cnt; ++j) {
            const int2 pv = tp[j];                 // uniform -> s_load_dwordx2
            const float vv = __int_as_float(pv.y);
            const float* xb = xs + pv.x + tid;     // lane-consecutive: 2-way bank alias (free)
            #pragma unroll
            for (int r = 0; r < 8; ++r) acc[r] += vv * xb[256 * r];
        }
        __half* ob = outT + ((size_t)row * 5 + sl) * T + tid;
        #pragma unroll
        for (int r = 0; r < 8; ++r) ob[256 * r] = __float2half(acc[r]);
    }
}

// ---------------- kernel 4: outT[row][s][t] -> out[n][t][c][s] (coalesced both sides) ----------------
__global__ __launch_bounds__(256) void cwt_fix(const __half* __restrict__ outT,
                                               float* __restrict__ out) {
    __shared__ float tile[16 * 320];              // 20.5 KB: [tt][c*5+s]
    const int b  = blockIdx.x;                    // 0..2047
    const int n  = b >> 7;
    const int t0 = (b & 127) << 4;
    const int tid = threadIdx.x;

    for (int sg = tid; sg < 320; sg += 256) {     // sg = c*5+s
        const uint4* src = (const uint4*)(outT + ((size_t)n * 320 + sg) * T + t0);
        uint4 v0 = src[0], v1 = src[1];           // 16 halves = 16 t's
        const __half* h0 = (const __half*)&v0;
        const __half* h1 = (const __half*)&v1;
        #pragma unroll
        for (int tt = 0; tt < 8; ++tt) tile[tt * 320 + sg] = __half2float(h0[tt]);
        #pragma unroll
        for (int tt = 0; tt < 8; ++tt) tile[(tt + 8) * 320 + sg] = __half2float(h1[tt]);
    }
    __syncthreads();
    float4* dst = (float4*)(out + (size_t)(n * T + t0) * 320);
    const float4* tl = (const float4*)tile;
    for (int k = tid; k < 1280; k += 256) dst[k] = tl[k];
}

// ---------------- launch ----------------
extern "C" void kernel_launch(void* const* d_in, const int* in_sizes, int n_in,
                              void* d_out, int out_size, void* d_ws, size_t ws_size,
                              hipStream_t stream) {
    const float* x = (const float*)d_in[0];
    float* out = (float*)d_out;
    char* ws = (char*)d_ws;

    int*    counts = (int*)ws;
    int2*   taps   = (int2*)(ws + WS_TAPS);
    __half* xT     = (__half*)(ws + WS_XT);
    __half* outT   = (__half*)(ws + WS_OUTT);

    cwt_init_taps<<<1, 1024, 0, stream>>>(taps, counts);
    cwt_transpose<<<512, 256, 0, stream>>>(x, xT);
    cwt_conv<<<NROWS, 256, 0, stream>>>(xT, taps, counts, outT);
    cwt_fix<<<2048, 256, 0, stream>>>(outT, out);
}

// Round 2
// 206.088 us; speedup vs baseline: 2.4902x; 2.4902x over previous
//
#include <hip/hip_runtime.h>
#include <hip/hip_fp16.h>
#include <math.h>

// ---------------- problem constants ----------------
// x: (16, 2048, 64) f32  -> out: (16, 2048, 64, 5) f32
// scales = {1,27,76,167,336}; morlet int_psi, n=1024, [-8,8]
#define NB    16
#define T     2048
#define NC    64
#define NROWS (NB*NC)     // 1024
#define PADL2 2696        // left zero-pad (halves), mult of 8 for b128 stores
#define XSH_N 7440        // padded row length (halves): 2696+2048+right-pad -> mult of 8

// Toeplitz-block GEMM tables (derived exactly from integer tap geometry):
//   posoff_s = PADL2-8s-1; q0 = posoff; qL = 8s+PADL2-? (= posoff+16s+1)
//   Pbase = q0>>4;  K_s = round_up(15 + qL - 16*Pbase + 1, 32)
#define K0 64
#define K1 480
#define K2 1248
#define K3 2720
#define K4 5408
// W halves offsets (16*K prefix sums), total 158720 halves = 317440 B (+slack)
#define WTOT_U4 19904     // uint4 count to zero (covers 960 B tail slack)

// ws layout (bytes):
//   0        : __half W[158720+slack]               (~318 KB)
//   512 KB   : __half xT[1024][2048]                (4 MB)
//   512KB+4MB: __half outT[1024][5][2048]           (20 MB)   total ~24.5 MB
#define WS_XT    (1u<<19)
#define WS_OUTT  ((1u<<19) + (1u<<22))

typedef _Float16 half8  __attribute__((ext_vector_type(8)));
typedef _Float16 half4v __attribute__((ext_vector_type(4)));
typedef float    f32x4  __attribute__((ext_vector_type(4)));

// ---------------- kernel 1: build packed Toeplitz weights W ----------------
// Replicates reference float64 arithmetic EXACTLY (round-1 verified):
//   t = linspace(-8,8,1024); step = t[1]-t[0]  ((-8+16/1023)+8 roundtrip!)
//   j_i = int64(i/(s*step)); taps g_i over i in [0,L], L=16s+1:
//   g_0=+sq*k[0]; g_i=sq*(k[j_i]-k[j_{i-1}]); g_L=-sq*k[j_{L-1}];  sq=sqrt(s)
// Scatter: W[sl][b][ (b + i + posoff) - 16*Pbase ] = g_i  for b in [0,16).
__global__ __launch_bounds__(1024) void cwt_init_w(__half* __restrict__ W) {
    __shared__ double ps[1024];
    __shared__ double sc[1024];
    __shared__ float  k32[1024];
    const int tid = threadIdx.x;

    // zero W (and slack) — same block scatters after the barrier
    uint4* W4 = (uint4*)W;
    const uint4 z = make_uint4(0u, 0u, 0u, 0u);
    for (int i = tid; i < WTOT_U4; i += 1024) W4[i] = z;

    const double delta = 16.0 / 1023.0;
    double t = (tid == 1023) ? 8.0 : (-8.0 + delta * (double)tid);
    ps[tid] = exp(-0.5 * t * t) * cos(5.0 * t);
    __syncthreads();

    double* a = ps; double* b = sc;
    for (int off = 1; off < 1024; off <<= 1) {
        double v = a[tid];
        if (tid >= off) v += a[tid - off];
        b[tid] = v;
        __syncthreads();
        double* tmp = a; a = b; b = tmp;
    }
    const double step = ((-8.0 + delta) + 8.0);   // NOT exactly 16/1023
    k32[tid] = (float)(a[tid] * step);
    __syncthreads();

    constexpr int SC[5]   = {1, 27, 76, 167, 336};
    constexpr int KS[5]   = {K0, K1, K2, K3, K4};
    constexpr int WOFF[5] = {0, 1024, 8704, 28672, 72192};
    constexpr int PB[5]   = {167, 154, 130, 84, 0};
    for (int sl = 0; sl < 5; ++sl) {
        const int s = SC[sl];
        const int L = 16 * s + 1;
        const double c = (double)s * step;
        const float sq = (float)sqrt((double)s);
        const int posoff = PADL2 - 8 * s - 1;
        const int kb0 = posoff - 16 * PB[sl];
        __half* wb = W + WOFF[sl];
        const int Ks = KS[sl];
        for (int i = tid; i <= L; i += 1024) {
            float g; bool wr = true;
            if (i == 0) {
                g = sq * k32[0];
            } else if (i == L) {
                long long jl = (long long)((double)(L - 1) / c);
                if (jl > 1023) jl = 1023;
                g = -sq * k32[jl];
            } else {
                long long j1 = (long long)((double)i / c);
                long long j0 = (long long)((double)(i - 1) / c);
                if (j1 > 1023) j1 = 1023;
                if (j0 > 1023) j0 = 1023;
                wr = (j1 > j0);
                g = sq * (k32[j1] - k32[j0]);
            }
            if (wr) {
                const __half hg = __float2half(g);
                const int kb = kb0 + i;
                #pragma unroll
                for (int bb = 0; bb < 16; ++bb)
                    wb[bb * Ks + kb + bb] = hg;
            }
        }
    }
}

// ---------------- kernel 2: transpose x(n,t,c) -> xT[(n*64+c)][t] as fp16 ----------------
__global__ __launch_bounds__(256) void cwt_transpose(const float* __restrict__ x,
                                                     __half* __restrict__ xT) {
    __shared__ float tile[64 * 65];
    const int b  = blockIdx.x;                    // 0..511
    const int n  = b >> 5;
    const int t0 = (b & 31) << 6;
    const int tid = threadIdx.x;

    const float4* src = (const float4*)(x + ((size_t)(n * T + t0)) * NC);
    #pragma unroll
    for (int k = 0; k < 4; ++k) {
        float4 v = src[tid + 256 * k];
        const int flat = (tid + 256 * k) * 4;
        const int tt = flat >> 6, c = flat & 63;
        tile[tt * 65 + c + 0] = v.x;
        tile[tt * 65 + c + 1] = v.y;
        tile[tt * 65 + c + 2] = v.z;
        tile[tt * 65 + c + 3] = v.w;
    }
    __syncthreads();
    const int lane = tid & 63, w = tid >> 6;
    for (int cc = w; cc < 64; cc += 4) {
        xT[((size_t)(n * 64 + cc)) * T + t0 + lane] = __float2half(tile[lane * 65 + cc]);
    }
}

// ---------------- kernel 3: Toeplitz-block MFMA conv ----------------
// Out[16A+b] = sum_k W[b][k] * xsh[16*(A+Pbase)+k], per scale.
// mfma_f32_16x16x32_f16: A-frag = W rows (LDS-staged chunk), B-frag = raw xsh.
// Block = 1 signal row, 4 waves x 2 A-tiles (A in [32w,32w+32)).
__global__ __launch_bounds__(256) void cwt_conv_mfma(const __half* __restrict__ xT,
                                                     const __half* __restrict__ Wg,
                                                     __half* __restrict__ outT) {
    constexpr int KS[5]   = {K0, K1, K2, K3, K4};
    constexpr int WOFF[5] = {0, 1024, 8704, 28672, 72192};
    constexpr int PB[5]   = {167, 154, 130, 84, 0};

    __shared__ _Float16 xsh[XSH_N];               // 14880 B
    __shared__ _Float16 wbuf[16 * 520];           // 16640 B  (+8/row pad)
    __shared__ _Float16 ostage[2048];             // 4096 B (512/wave)
    const int tid  = threadIdx.x;
    const int row  = blockIdx.x;
    const int lane = tid & 63;
    const int w    = tid >> 6;
    const int mcol = lane & 15;                   // M (W-row b) for A-frag; N (A-col) for B-frag
    const int grp  = lane >> 4;                   // k-subgroup

    // ---- stage padded signal row (fp16) ----
    {
        uint4* x4 = (uint4*)xsh;
        const uint4 z = make_uint4(0u, 0u, 0u, 0u);
        for (int i = tid; i < XSH_N / 8; i += 256)
            if (i < PADL2 / 8 || i >= (PADL2 + T) / 8) x4[i] = z;
        x4[PADL2 / 8 + tid] = ((const uint4*)(xT + (size_t)row * T))[tid];
    }

    for (int sl = 0; sl < 5; ++sl) {
        const int K   = KS[sl];
        const int nch = (K + 511) >> 9;
        const __half* wsrc = Wg + WOFF[sl];
        f32x4 acc0 = {0.f, 0.f, 0.f, 0.f};
        f32x4 acc1 = {0.f, 0.f, 0.f, 0.f};

        // prefetch W chunk 0 into registers (rows 4p+w, 512-halves columns)
        uint4 pre[4];
        #pragma unroll
        for (int p = 0; p < 4; ++p)
            pre[p] = *(const uint4*)(wsrc + (size_t)(4 * p + w) * K + lane * 8);

        for (int c = 0; c < nch; ++c) {
            __syncthreads();                       // all waves done reading wbuf
            #pragma unroll
            for (int p = 0; p < 4; ++p)
                *(uint4*)(wbuf + (4 * p + w) * 520 + lane * 8) = pre[p];
            __syncthreads();
            if (c + 1 < nch) {
                const int k0n = (c + 1) << 9;
                #pragma unroll
                for (int p = 0; p < 4; ++p)
                    pre[p] = *(const uint4*)(wsrc + (size_t)(4 * p + w) * K + k0n + lane * 8);
            }
            const int k0 = c << 9;
            const int Kc = (K - k0 < 512) ? (K - k0) : 512;
            const _Float16* ab  = wbuf + mcol * 520 + 8 * grp;
            const _Float16* xb0 = xsh + 16 * (PB[sl] + 32 * w + mcol) + k0 + 8 * grp;
            for (int kk = 0; kk < Kc; kk += 32) {
                half8 af = *(const half8*)(ab + kk);
                half8 b0 = *(const half8*)(xb0 + kk);
                half8 b1 = *(const half8*)(xb0 + 256 + kk);
                acc0 = __builtin_amdgcn_mfma_f32_16x16x32_f16(af, b0, acc0, 0, 0, 0);
                acc1 = __builtin_amdgcn_mfma_f32_16x16x32_f16(af, b1, acc1, 0, 0, 0);
            }
        }
        // ---- epilogue: D(col=lane&15 -> A, row=grp*4+reg -> b); t = 16A+b ----
        _Float16* os = ostage + 512 * w;          // wave-local, no barrier needed
        half4v h0, h1;
        #pragma unroll
        for (int r = 0; r < 4; ++r) { h0[r] = (_Float16)acc0[r]; h1[r] = (_Float16)acc1[r]; }
        *(half4v*)(os + 16 * mcol + 4 * grp) = h0;          // tile0: t' = 16n + 4q + r
        *(half4v*)(os + 256 + 16 * mcol + 4 * grp) = h1;    // tile1
        half8 o = *(const half8*)(os + 8 * lane);
        *(half8*)(outT + ((size_t)row * 5 + sl) * T + 512 * w + 8 * lane) = o;
    }
}

// ---------------- kernel 4: outT[row][s][t] -> out[n][t][c][s] ----------------
__global__ __launch_bounds__(256) void cwt_fix(const __half* __restrict__ outT,
                                               float* __restrict__ out) {
    __shared__ float tile[16 * 320];
    const int b  = blockIdx.x;                    // 0..2047
    const int n  = b >> 7;
    const int t0 = (b & 127) << 4;
    const int tid = threadIdx.x;

    for (int sg = tid; sg < 320; sg += 256) {     // sg = c*5+s
        const uint4* src = (const uint4*)(outT + ((size_t)n * 320 + sg) * T + t0);
        uint4 v0 = src[0], v1 = src[1];
        const __half* h0 = (const __half*)&v0;
        const __half* h1 = (const __half*)&v1;
        #pragma unroll
        for (int tt = 0; tt < 8; ++tt) tile[tt * 320 + sg] = __half2float(h0[tt]);
        #pragma unroll
        for (int tt = 0; tt < 8; ++tt) tile[(tt + 8) * 320 + sg] = __half2float(h1[tt]);
    }
    __syncthreads();
    float4* dst = (float4*)(out + (size_t)(n * T + t0) * 320);
    const float4* tl = (const float4*)tile;
    for (int k = tid; k < 1280; k += 256) dst[k] = tl[k];
}

// ---------------- launch ----------------
extern "C" void kernel_launch(void* const* d_in, const int* in_sizes, int n_in,
                              void* d_out, int out_size, void* d_ws, size_t ws_size,
                              hipStream_t stream) {
    const float* x = (const float*)d_in[0];
    float* out = (float*)d_out;
    char* ws = (char*)d_ws;

    __half* W    = (__half*)ws;
    __half* xT   = (__half*)(ws + WS_XT);
    __half* outT = (__half*)(ws + WS_OUTT);

    cwt_init_w<<<1, 1024, 0, stream>>>(W);
    cwt_transpose<<<512, 256, 0, stream>>>(x, xT);
    cwt_conv_mfma<<<NROWS, 256, 0, stream>>>(xT, W, outT);
    cwt_fix<<<2048, 256, 0, stream>>>(outT, out);
}

// Round 4
// 198.109 us; speedup vs baseline: 2.5905x; 1.0403x over previous
//
#include <hip/hip_runtime.h>
#include <hip/hip_fp16.h>
#include <math.h>

// ---------------- problem constants ----------------
// x: (16, 2048, 64) f32  -> out: (16, 2048, 64, 5) f32
// scales = {1,27,76,167,336}; morlet int_psi, n=1024, [-8,8]
#define NB    16
#define T     2048
#define NC    64
#define NROWS (NB*NC)     // 1024
#define PADL2 2696        // left zero-pad (halves), mult of 8
#define XSH_N 7440        // 2696 + 2048 + right pad; max B index 16*127+5407 = 7439 < 7440

// Unified global-k chunk axis: chunk c covers k in [32c, 32c+32), c in [0,169).
// k = b + i + posoff, posoff = 2695-8s; k_min=posoff, k_max=8s+2711.
// Exec order: largest scale first (nested ranges -> alive set is always a prefix).
//   sl:      0      1      2      3      4
//   scale:   336    167    76     27     1
//   CLO:     0      42     65     77     83     (first alive chunk; r3 bug was 70)
//   NCH:     169    85     39     15     2
//   KS2:     5408   2720   1248   480    64     (=32*NCH, W row stride)
//   kl_max:  5399   2703   1239   463    63     (all < KS2: no overflow)
//   WOFF:    0      86528  130048 150016 157696 (halves; total 158720 = 19840 uint4)
//   outslot: 4      3      2      1      0      (output s-axis is ascending scale)
#define WTOT_U4 19840

// ws layout (bytes):
//   0        : __half W[158720]                    (~310 KB)
//   512 KB   : __half xT[1024][2048]               (4 MB)
//   512KB+4MB: __half outT[1024][5][2048]          (20 MB)
#define WS_XT    (1u<<19)
#define WS_OUTT  ((1u<<19) + (1u<<22))

typedef _Float16 half8  __attribute__((ext_vector_type(8)));
typedef _Float16 half4v __attribute__((ext_vector_type(4)));
typedef float    f32x4  __attribute__((ext_vector_type(4)));

// ---------------- kernel 1: build packed Toeplitz weights W ----------------
// Replicates reference float64 arithmetic EXACTLY (round-1/2 verified):
//   t = linspace(-8,8,1024); step = t[1]-t[0]  ((-8+16/1023)+8 roundtrip!)
//   j_i = int64(i/(s*step)); taps g_i over i in [0,L], L=16s+1:
//   g_0=+sq*k[0]; g_i=sq*(k[j_i]-k[j_{i-1}]); g_L=-sq*k[j_{L-1}];  sq=sqrt(s)
// Scatter: W[sl][b][ b + i + posoff - 32*CLO[sl] ] = g_i  for b in [0,16).
__global__ __launch_bounds__(1024) void cwt_init_w(__half* __restrict__ W) {
    __shared__ double ps[1024];
    __shared__ double sc[1024];
    __shared__ float  k32[1024];
    const int tid = threadIdx.x;

    uint4* W4 = (uint4*)W;
    const uint4 z = make_uint4(0u, 0u, 0u, 0u);
    for (int i = tid; i < WTOT_U4; i += 1024) W4[i] = z;

    const double delta = 16.0 / 1023.0;
    double t = (tid == 1023) ? 8.0 : (-8.0 + delta * (double)tid);
    ps[tid] = exp(-0.5 * t * t) * cos(5.0 * t);
    __syncthreads();

    double* a = ps; double* b = sc;
    for (int off = 1; off < 1024; off <<= 1) {
        double v = a[tid];
        if (tid >= off) v += a[tid - off];
        b[tid] = v;
        __syncthreads();
        double* tmp = a; a = b; b = tmp;
    }
    const double step = ((-8.0 + delta) + 8.0);   // NOT exactly 16/1023
    k32[tid] = (float)(a[tid] * step);
    __syncthreads();

    constexpr int SCe[5]   = {336, 167, 76, 27, 1};
    constexpr int KS2[5]   = {5408, 2720, 1248, 480, 64};
    constexpr int WOFFe[5] = {0, 86528, 130048, 150016, 157696};
    constexpr int CLOe[5]  = {0, 42, 65, 77, 83};
    for (int sl = 0; sl < 5; ++sl) {
        const int s = SCe[sl];
        const int L = 16 * s + 1;
        const double c = (double)s * step;
        const float sq = (float)sqrt((double)s);
        const int posoff = PADL2 - 8 * s - 1;
        const int kb0 = posoff - 32 * CLOe[sl];
        __half* wb = W + WOFFe[sl];
        const int Ks = KS2[sl];
        for (int i = tid; i <= L; i += 1024) {
            float g; bool wr = true;
            if (i == 0) {
                g = sq * k32[0];
            } else if (i == L) {
                long long jl = (long long)((double)(L - 1) / c);
                if (jl > 1023) jl = 1023;
                g = -sq * k32[jl];
            } else {
                long long j1 = (long long)((double)i / c);
                long long j0 = (long long)((double)(i - 1) / c);
                if (j1 > 1023) j1 = 1023;
                if (j0 > 1023) j0 = 1023;
                wr = (j1 > j0);
                g = sq * (k32[j1] - k32[j0]);
            }
            if (wr) {
                const __half hg = __float2half(g);
                const int kb = kb0 + i;
                #pragma unroll
                for (int bb = 0; bb < 16; ++bb)
                    wb[bb * Ks + kb + bb] = hg;
            }
        }
    }
}

// ---------------- kernel 2: transpose x(n,t,c) -> xT[(n*64+c)][t] as fp16 ----------------
__global__ __launch_bounds__(256) void cwt_transpose(const float* __restrict__ x,
                                                     __half* __restrict__ xT) {
    __shared__ float tile[64 * 65];
    const int b  = blockIdx.x;                    // 0..511
    const int n  = b >> 5;
    const int t0 = (b & 31) << 6;
    const int tid = threadIdx.x;

    const float4* src = (const float4*)(x + ((size_t)(n * T + t0)) * NC);
    #pragma unroll
    for (int k = 0; k < 4; ++k) {
        float4 v = src[tid + 256 * k];
        const int flat = (tid + 256 * k) * 4;
        const int tt = flat >> 6, c = flat & 63;
        tile[tt * 65 + c + 0] = v.x;
        tile[tt * 65 + c + 1] = v.y;
        tile[tt * 65 + c + 2] = v.z;
        tile[tt * 65 + c + 3] = v.w;
    }
    __syncthreads();
    const int lane = tid & 63, w = tid >> 6;
    for (int cc = w; cc < 64; cc += 4) {
        xT[((size_t)(n * 64 + cc)) * T + t0 + lane] = __float2half(tile[lane * 65 + cc]);
    }
}

// ---------------- kernel 3: Toeplitz-block MFMA conv, unified k-axis ----------------
// Out_sl[16A+b] = sum_k W_sl[b][k-32*CLO] * xsh[16A+k].
// A-frag (W) read straight from global (L1/L2-resident, all waves share it);
// B-frag (signal) from LDS. No barriers after staging. Alive-scale set per
// chunk is a prefix of exec order (nested ranges) -> constant-N segments,
// fully static acc indexing.
template<int N>
__device__ __forceinline__ void conv_seg(int c0, int c1,
                                         const _Float16* __restrict__ xb,
                                         const _Float16* const (&ap)[5],
                                         f32x4 (&acc)[5][2]) {
    #pragma unroll 2
    for (int c = c0; c < c1; ++c) {
        const int ko = c << 5;
        half8 b0 = *(const half8*)(xb + ko);
        half8 b1 = *(const half8*)(xb + 256 + ko);
        #pragma unroll
        for (int sl = 0; sl < N; ++sl) {
            half8 af = *(const half8*)(ap[sl] + ko);
            acc[sl][0] = __builtin_amdgcn_mfma_f32_16x16x32_f16(af, b0, acc[sl][0], 0, 0, 0);
            acc[sl][1] = __builtin_amdgcn_mfma_f32_16x16x32_f16(af, b1, acc[sl][1], 0, 0, 0);
        }
    }
}

__global__ __launch_bounds__(256, 4) void cwt_conv_mfma(const __half* __restrict__ xT,
                                                        const __half* __restrict__ Wg,
                                                        __half* __restrict__ outT) {
    constexpr int KS2[5]   = {5408, 2720, 1248, 480, 64};
    constexpr int WOFFe[5] = {0, 86528, 130048, 150016, 157696};
    constexpr int CLOe[5]  = {0, 42, 65, 77, 83};
    constexpr int OS[5]    = {4, 3, 2, 1, 0};

    __shared__ _Float16 xsh[XSH_N];               // 14880 B
    __shared__ _Float16 ostage[2048];             // 4096 B (512/wave)
    const int tid  = threadIdx.x;
    const int row  = blockIdx.x;
    const int lane = tid & 63;
    const int w    = tid >> 6;
    const int mcol = lane & 15;                   // A-frag: W row b;  B-frag: col n
    const int grp  = lane >> 4;                   // k-subgroup

    // ---- stage padded signal row (fp16) ----
    {
        uint4* x4 = (uint4*)xsh;
        const uint4 z = make_uint4(0u, 0u, 0u, 0u);
        for (int i = tid; i < XSH_N / 8; i += 256)
            if (i < PADL2 / 8 || i >= (PADL2 + T) / 8) x4[i] = z;
        x4[PADL2 / 8 + tid] = ((const uint4*)(xT + (size_t)row * T))[tid];
    }
    __syncthreads();

    // per-lane operand bases
    const _Float16* xb = xsh + 512 * w + 16 * mcol + 8 * grp;   // tile0; tile1 = +256
    const _Float16* ap[5];
    #pragma unroll
    for (int sl = 0; sl < 5; ++sl)
        ap[sl] = (const _Float16*)Wg + WOFFe[sl] + mcol * KS2[sl] + 8 * grp
                 - (CLOe[sl] << 5);

    f32x4 acc[5][2];
    #pragma unroll
    for (int sl = 0; sl < 5; ++sl)
        #pragma unroll
        for (int tt = 0; tt < 2; ++tt)
            acc[sl][tt] = (f32x4){0.f, 0.f, 0.f, 0.f};

    // constant-alive-count segments over the unified chunk axis
    // alive: 336:[0,169) 167:[42,127) 76:[65,104) 27:[77,92) 1:[83,85)
    conv_seg<1>(  0,  42, xb, ap, acc);
    conv_seg<2>( 42,  65, xb, ap, acc);
    conv_seg<3>( 65,  77, xb, ap, acc);
    conv_seg<4>( 77,  83, xb, ap, acc);
    conv_seg<5>( 83,  85, xb, ap, acc);
    conv_seg<4>( 85,  92, xb, ap, acc);
    conv_seg<3>( 92, 104, xb, ap, acc);
    conv_seg<2>(104, 127, xb, ap, acc);
    conv_seg<1>(127, 169, xb, ap, acc);

    // ---- epilogue (round-2 verified): D col=lane&15 -> A, row=grp*4+r -> b ----
    _Float16* os = ostage + 512 * w;              // wave-local, no barrier needed
    #pragma unroll
    for (int sl = 0; sl < 5; ++sl) {
        half4v h0, h1;
        #pragma unroll
        for (int r = 0; r < 4; ++r) { h0[r] = (_Float16)acc[sl][0][r]; h1[r] = (_Float16)acc[sl][1][r]; }
        *(half4v*)(os + 16 * mcol + 4 * grp) = h0;
        *(half4v*)(os + 256 + 16 * mcol + 4 * grp) = h1;
        half8 o = *(const half8*)(os + 8 * lane);
        *(half8*)(outT + ((size_t)row * 5 + OS[sl]) * T + 512 * w + 8 * lane) = o;
    }
}

// ---------------- kernel 4: outT[row][s][t] -> out[n][t][c][s] ----------------
__global__ __launch_bounds__(256) void cwt_fix(const __half* __restrict__ outT,
                                               float* __restrict__ out) {
    __shared__ float tile[16 * 320];
    const int b  = blockIdx.x;                    // 0..2047
    const int n  = b >> 7;
    const int t0 = (b & 127) << 4;
    const int tid = threadIdx.x;

    for (int sg = tid; sg < 320; sg += 256) {     // sg = c*5+s
        const uint4* src = (const uint4*)(outT + ((size_t)n * 320 + sg) * T + t0);
        uint4 v0 = src[0], v1 = src[1];
        const __half* h0 = (const __half*)&v0;
        const __half* h1 = (const __half*)&v1;
        #pragma unroll
        for (int tt = 0; tt < 8; ++tt) tile[tt * 320 + sg] = __half2float(h0[tt]);
        #pragma unroll
        for (int tt = 0; tt < 8; ++tt) tile[(tt + 8) * 320 + sg] = __half2float(h1[tt]);
    }
    __syncthreads();
    float4* dst = (float4*)(out + (size_t)(n * T + t0) * 320);
    const float4* tl = (const float4*)tile;
    for (int k = tid; k < 1280; k += 256) dst[k] = tl[k];
}

// ---------------- launch ----------------
extern "C" void kernel_launch(void* const* d_in, const int* in_sizes, int n_in,
                              void* d_out, int out_size, void* d_ws, size_t ws_size,
                              hipStream_t stream) {
    const float* x = (const float*)d_in[0];
    float* out = (float*)d_out;
    char* ws = (char*)d_ws;

    __half* W    = (__half*)ws;
    __half* xT   = (__half*)(ws + WS_XT);
    __half* outT = (__half*)(ws + WS_OUTT);

    cwt_init_w<<<1, 1024, 0, stream>>>(W);
    cwt_transpose<<<512, 256, 0, stream>>>(x, xT);
    cwt_conv_mfma<<<NROWS, 256, 0, stream>>>(xT, W, outT);
    cwt_fix<<<2048, 256, 0, stream>>>(outT, out);
}

// Round 5
// 186.820 us; speedup vs baseline: 2.7470x; 1.0604x over previous
//
#include <hip/hip_runtime.h>
#include <hip/hip_fp16.h>
#include <math.h>

// ---------------- problem constants ----------------
// x: (16, 2048, 64) f32  -> out: (16, 2048, 64, 5) f32
// scales = {1,27,76,167,336}; morlet int_psi, n=1024, [-8,8]
#define NB    16
#define T     2048
#define NC    64
#define NROWS (NB*NC)     // 1024
#define PADL2 2696        // left zero-pad (halves), mult of 8
#define XSH_N 7440        // 2696 + 2048 + right pad; max B index 16*127+5407 = 7439 < 7440

// Unified global-k chunk axis: chunk c covers k in [32c, 32c+32), c in [0,169).
// k = b + i + posoff, posoff = 2695-8s; k_min=posoff, k_max=8s+2711.
// Exec order: largest scale first (nested ranges -> alive set is always a prefix).
//   sl:      0      1      2      3      4
//   scale:   336    167    76     27     1
//   CLO:     0      42     65     77     83
//   KS2:     5408   2720   1248   480    64     (=32*NCH, W row stride)
//   WOFF:    0      86528  130048 150016 157696 (halves; total 158720 = 19840 uint4)
//   outslot: 4      3      2      1      0      (output s-axis is ascending scale)
#define WTOT_U4 19840

// ws layout (bytes):
//   0        : __half W[158720]                    (~310 KB)
//   512 KB   : __half xT[1024][2048]               (4 MB)
//   512KB+4MB: __half outT[1024][5][2048]          (20 MB)
#define WS_XT    (1u<<19)
#define WS_OUTT  ((1u<<19) + (1u<<22))

typedef _Float16 half8  __attribute__((ext_vector_type(8)));
typedef _Float16 half4v __attribute__((ext_vector_type(4)));
typedef float    f32x4  __attribute__((ext_vector_type(4)));

// ---------------- kernel 1: build packed Toeplitz weights W ----------------
// Replicates reference float64 arithmetic EXACTLY (round-1/2/4 verified):
//   t = linspace(-8,8,1024); step = t[1]-t[0]  ((-8+16/1023)+8 roundtrip!)
//   j_i = int64(i/(s*step)); taps g_i over i in [0,L], L=16s+1:
//   g_0=+sq*k[0]; g_i=sq*(k[j_i]-k[j_{i-1}]); g_L=-sq*k[j_{L-1}];  sq=sqrt(s)
// Scatter: W[sl][b][ b + i + posoff - 32*CLO[sl] ] = g_i  for b in [0,16).
__global__ __launch_bounds__(1024) void cwt_init_w(__half* __restrict__ W) {
    __shared__ double ps[1024];
    __shared__ double sc[1024];
    __shared__ float  k32[1024];
    const int tid = threadIdx.x;

    uint4* W4 = (uint4*)W;
    const uint4 z = make_uint4(0u, 0u, 0u, 0u);
    for (int i = tid; i < WTOT_U4; i += 1024) W4[i] = z;

    const double delta = 16.0 / 1023.0;
    double t = (tid == 1023) ? 8.0 : (-8.0 + delta * (double)tid);
    ps[tid] = exp(-0.5 * t * t) * cos(5.0 * t);
    __syncthreads();

    double* a = ps; double* b = sc;
    for (int off = 1; off < 1024; off <<= 1) {
        double v = a[tid];
        if (tid >= off) v += a[tid - off];
        b[tid] = v;
        __syncthreads();
        double* tmp = a; a = b; b = tmp;
    }
    const double step = ((-8.0 + delta) + 8.0);   // NOT exactly 16/1023
    k32[tid] = (float)(a[tid] * step);
    __syncthreads();

    constexpr int SCe[5]   = {336, 167, 76, 27, 1};
    constexpr int KS2[5]   = {5408, 2720, 1248, 480, 64};
    constexpr int WOFFe[5] = {0, 86528, 130048, 150016, 157696};
    constexpr int CLOe[5]  = {0, 42, 65, 77, 83};
    for (int sl = 0; sl < 5; ++sl) {
        const int s = SCe[sl];
        const int L = 16 * s + 1;
        const double c = (double)s * step;
        const float sq = (float)sqrt((double)s);
        const int posoff = PADL2 - 8 * s - 1;
        const int kb0 = posoff - 32 * CLOe[sl];
        __half* wb = W + WOFFe[sl];
        const int Ks = KS2[sl];
        for (int i = tid; i <= L; i += 1024) {
            float g; bool wr = true;
            if (i == 0) {
                g = sq * k32[0];
            } else if (i == L) {
                long long jl = (long long)((double)(L - 1) / c);
                if (jl > 1023) jl = 1023;
                g = -sq * k32[jl];
            } else {
                long long j1 = (long long)((double)i / c);
                long long j0 = (long long)((double)(i - 1) / c);
                if (j1 > 1023) j1 = 1023;
                if (j0 > 1023) j0 = 1023;
                wr = (j1 > j0);
                g = sq * (k32[j1] - k32[j0]);
            }
            if (wr) {
                const __half hg = __float2half(g);
                const int kb = kb0 + i;
                #pragma unroll
                for (int bb = 0; bb < 16; ++bb)
                    wb[bb * Ks + kb + bb] = hg;
            }
        }
    }
}

// ---------------- kernel 2: transpose x(n,t,c) -> xT[(n*64+c)][t] as fp16 ----------------
__global__ __launch_bounds__(256) void cwt_transpose(const float* __restrict__ x,
                                                     __half* __restrict__ xT) {
    __shared__ float tile[64 * 65];
    const int b  = blockIdx.x;                    // 0..511
    const int n  = b >> 5;
    const int t0 = (b & 31) << 6;
    const int tid = threadIdx.x;

    const float4* src = (const float4*)(x + ((size_t)(n * T + t0)) * NC);
    #pragma unroll
    for (int k = 0; k < 4; ++k) {
        float4 v = src[tid + 256 * k];
        const int flat = (tid + 256 * k) * 4;
        const int tt = flat >> 6, c = flat & 63;
        tile[tt * 65 + c + 0] = v.x;
        tile[tt * 65 + c + 1] = v.y;
        tile[tt * 65 + c + 2] = v.z;
        tile[tt * 65 + c + 3] = v.w;
    }
    __syncthreads();
    const int lane = tid & 63, w = tid >> 6;
    for (int cc = w; cc < 64; cc += 4) {
        xT[((size_t)(n * 64 + cc)) * T + t0 + lane] = __float2half(tile[lane * 65 + cc]);
    }
}

// ---------------- kernel 3: Toeplitz-block MFMA conv, wide-N waves ----------------
// Out_sl[16A+b] = sum_k W_sl[b][k-32*CLO] * xsh[16A+k].
// Block = 1 row, 2 waves; each wave owns N=64 output cols (4 MFMA B-tiles), so
// each global A-frag load feeds 4 MFMAs (round-4: 2) and per-CU A-load count
// drops 4x. Depth-1 register prefetch of next chunk's A-frags hides L1/L2
// latency. B-frags from LDS; no barriers after staging.
template<int N>
__device__ __forceinline__ void conv_seg(int c0, int c1,
                                         const _Float16* __restrict__ xb,
                                         const _Float16* const (&ap)[5],
                                         f32x4 (&acc)[5][4]) {
    half8 a_cur[N], a_nxt[N];
    #pragma unroll
    for (int sl = 0; sl < N; ++sl)
        a_cur[sl] = *(const half8*)(ap[sl] + (c0 << 5));
    #pragma unroll 2
    for (int c = c0; c < c1; ++c) {
        const int cn = (c + 1 < c1) ? c + 1 : c;   // clamp: redundant reload, no OOB
        #pragma unroll
        for (int sl = 0; sl < N; ++sl)
            a_nxt[sl] = *(const half8*)(ap[sl] + (cn << 5));
        const int ko = c << 5;
        half8 b0 = *(const half8*)(xb + ko);
        half8 b1 = *(const half8*)(xb + 256 + ko);
        half8 b2 = *(const half8*)(xb + 512 + ko);
        half8 b3 = *(const half8*)(xb + 768 + ko);
        #pragma unroll
        for (int sl = 0; sl < N; ++sl) {
            acc[sl][0] = __builtin_amdgcn_mfma_f32_16x16x32_f16(a_cur[sl], b0, acc[sl][0], 0, 0, 0);
            acc[sl][1] = __builtin_amdgcn_mfma_f32_16x16x32_f16(a_cur[sl], b1, acc[sl][1], 0, 0, 0);
            acc[sl][2] = __builtin_amdgcn_mfma_f32_16x16x32_f16(a_cur[sl], b2, acc[sl][2], 0, 0, 0);
            acc[sl][3] = __builtin_amdgcn_mfma_f32_16x16x32_f16(a_cur[sl], b3, acc[sl][3], 0, 0, 0);
        }
        #pragma unroll
        for (int sl = 0; sl < N; ++sl) a_cur[sl] = a_nxt[sl];
    }
}

__global__ __launch_bounds__(128, 2) void cwt_conv_mfma(const __half* __restrict__ xT,
                                                        const __half* __restrict__ Wg,
                                                        __half* __restrict__ outT) {
    constexpr int KS2[5]   = {5408, 2720, 1248, 480, 64};
    constexpr int WOFFe[5] = {0, 86528, 130048, 150016, 157696};
    constexpr int CLOe[5]  = {0, 42, 65, 77, 83};
    constexpr int OS[5]    = {4, 3, 2, 1, 0};

    __shared__ _Float16 xsh[XSH_N];               // 14880 B
    __shared__ _Float16 ostage[2048];             // 4096 B (1024/wave)
    const int tid  = threadIdx.x;
    const int row  = blockIdx.x;
    const int lane = tid & 63;
    const int w    = tid >> 6;                    // wave 0/1: A-cols [64w, 64w+64)
    const int mcol = lane & 15;                   // A-frag: W row b;  B-frag: col n
    const int grp  = lane >> 4;                   // k-subgroup

    // ---- stage padded signal row (fp16): [0,337) zero, [337,593) data, [593,930) zero (uint4 idx) ----
    {
        uint4* x4 = (uint4*)xsh;
        const uint4 z = make_uint4(0u, 0u, 0u, 0u);
        for (int i = tid; i < XSH_N / 8; i += 128)
            if (i < PADL2 / 8 || i >= (PADL2 + T) / 8) x4[i] = z;
        const uint4* src = (const uint4*)(xT + (size_t)row * T);
        x4[PADL2 / 8 + tid] = src[tid];
        x4[PADL2 / 8 + 128 + tid] = src[128 + tid];
    }
    __syncthreads();

    // per-lane operand bases
    const _Float16* xb = xsh + 1024 * w + 16 * mcol + 8 * grp;  // tiles at +0,+256,+512,+768
    const _Float16* ap[5];
    #pragma unroll
    for (int sl = 0; sl < 5; ++sl)
        ap[sl] = (const _Float16*)Wg + WOFFe[sl] + mcol * KS2[sl] + 8 * grp
                 - (CLOe[sl] << 5);

    f32x4 acc[5][4];
    #pragma unroll
    for (int sl = 0; sl < 5; ++sl)
        #pragma unroll
        for (int j = 0; j < 4; ++j)
            acc[sl][j] = (f32x4){0.f, 0.f, 0.f, 0.f};

    // constant-alive-count segments over the unified chunk axis
    // alive: 336:[0,169) 167:[42,127) 76:[65,104) 27:[77,92) 1:[83,85)
    conv_seg<1>(  0,  42, xb, ap, acc);
    conv_seg<2>( 42,  65, xb, ap, acc);
    conv_seg<3>( 65,  77, xb, ap, acc);
    conv_seg<4>( 77,  83, xb, ap, acc);
    conv_seg<5>( 83,  85, xb, ap, acc);
    conv_seg<4>( 85,  92, xb, ap, acc);
    conv_seg<3>( 92, 104, xb, ap, acc);
    conv_seg<2>(104, 127, xb, ap, acc);
    conv_seg<1>(127, 169, xb, ap, acc);

    // ---- epilogue (round-2/4 verified): D col=lane&15 -> A-col n, row=grp*4+r -> b ----
    // tile j covers t' = 256j + 16n + b in [0,1024) within this wave's span.
    _Float16* os = ostage + 1024 * w;             // wave-local, no barrier needed
    #pragma unroll
    for (int sl = 0; sl < 5; ++sl) {
        #pragma unroll
        for (int j = 0; j < 4; ++j) {
            half4v h;
            #pragma unroll
            for (int r = 0; r < 4; ++r) h[r] = (_Float16)acc[sl][j][r];
            *(half4v*)(os + 256 * j + 16 * mcol + 4 * grp) = h;
        }
        half8 o0 = *(const half8*)(os + 8 * lane);
        half8 o1 = *(const half8*)(os + 512 + 8 * lane);
        __half* ob = outT + ((size_t)row * 5 + OS[sl]) * T + 1024 * w;
        *(half8*)(ob + 8 * lane) = o0;
        *(half8*)(ob + 512 + 8 * lane) = o1;
    }
}

// ---------------- kernel 4: outT[row][s][t] -> out[n][t][c][s] ----------------
__global__ __launch_bounds__(256) void cwt_fix(const __half* __restrict__ outT,
                                               float* __restrict__ out) {
    __shared__ float tile[16 * 320];
    const int b  = blockIdx.x;                    // 0..2047
    const int n  = b >> 7;
    const int t0 = (b & 127) << 4;
    const int tid = threadIdx.x;

    for (int sg = tid; sg < 320; sg += 256) {     // sg = c*5+s
        const uint4* src = (const uint4*)(outT + ((size_t)n * 320 + sg) * T + t0);
        uint4 v0 = src[0], v1 = src[1];
        const __half* h0 = (const __half*)&v0;
        const __half* h1 = (const __half*)&v1;
        #pragma unroll
        for (int tt = 0; tt < 8; ++tt) tile[tt * 320 + sg] = __half2float(h0[tt]);
        #pragma unroll
        for (int tt = 0; tt < 8; ++tt) tile[(tt + 8) * 320 + sg] = __half2float(h1[tt]);
    }
    __syncthreads();
    float4* dst = (float4*)(out + (size_t)(n * T + t0) * 320);
    const float4* tl = (const float4*)tile;
    for (int k = tid; k < 1280; k += 256) dst[k] = tl[k];
}

// ---------------- launch ----------------
extern "C" void kernel_launch(void* const* d_in, const int* in_sizes, int n_in,
                              void* d_out, int out_size, void* d_ws, size_t ws_size,
                              hipStream_t stream) {
    const float* x = (const float*)d_in[0];
    float* out = (float*)d_out;
    char* ws = (char*)d_ws;

    __half* W    = (__half*)ws;
    __half* xT   = (__half*)(ws + WS_XT);
    __half* outT = (__half*)(ws + WS_OUTT);

    cwt_init_w<<<1, 1024, 0, stream>>>(W);
    cwt_transpose<<<512, 256, 0, stream>>>(x, xT);
    cwt_conv_mfma<<<NROWS, 128, 0, stream>>>(xT, W, outT);
    cwt_fix<<<2048, 256, 0, stream>>>(outT, out);
}

// Round 6
// 143.450 us; speedup vs baseline: 3.5775x; 1.3023x over previous
//
#include <hip/hip_runtime.h>
#include <hip/hip_fp16.h>
#include <math.h>

// ---------------- problem constants ----------------
// x: (16, 2048, 64) f32  -> out: (16, 2048, 64, 5) f32
// scales = {1,27,76,167,336}; morlet int_psi, n=1024, [-8,8]
#define NB    16
#define T     2048
#define NC    64
#define NROWS (NB*NC)     // 1024
#define PADL2 2696        // left zero-pad (halves), mult of 8
#define XSH_N 7440        // 2696 + 2048 + right pad; max B index 16*127+5407 = 7439 < 7440

// Unified global-k chunk axis: chunk c covers k in [32c, 32c+32), c in [0,169).
// k = b + i + posoff, posoff = 2695-8s; k_min=posoff, k_max=8s+2711.
// Exec order: largest scale first (nested ranges -> alive set is always a prefix).
//   sl:      0      1      2      3      4
//   scale:   336    167    76     27     1
//   CLO:     0      42     65     77     83
//   KS2:     5408   2720   1248   480    64     (=32*NCH, W row stride)
//   WOFF:    0      86528  130048 150016 157696 (halves; total 158720 = 19840 uint4)
//   outslot: 4      3      2      1      0      (output s-axis is ascending scale)
#define WTOT_U4 19840

// ws layout (bytes):
//   0        : __half W[158720]                    (~310 KB)
//   512 KB   : __half xT[1024][2048]               (4 MB)
//   512KB+4MB: __half outT2[16][128][64][5][16]    (20 MB)  [n][tb][c][s][tt]
#define WS_XT    (1u<<19)
#define WS_OUTT  ((1u<<19) + (1u<<22))

typedef _Float16 half8  __attribute__((ext_vector_type(8)));
typedef _Float16 half4v __attribute__((ext_vector_type(4)));
typedef float    f32x4  __attribute__((ext_vector_type(4)));

// ---------------- kernel 1: fused W-build (block 0) + transpose (blocks 1..128) ----------------
// init: replicates reference float64 arithmetic EXACTLY (rounds 1/2/4 verified):
//   t = linspace(-8,8,1024); step = t[1]-t[0]  ((-8+16/1023)+8 roundtrip!)
//   j_i = int64(i/(s*step)); taps g_i over i in [0,L], L=16s+1:
//   g_0=+sq*k[0]; g_i=sq*(k[j_i]-k[j_{i-1}]); g_L=-sq*k[j_{L-1}];  sq=sqrt(s)
//   Scatter: W[sl][b][ b + i + posoff - 32*CLO[sl] ] = g_i  for b in [0,16).
// transpose: x(n,t,c) -> xT[(n*64+c)][t] as fp16; 4 tiles per block (1024 thr).
__global__ __launch_bounds__(1024) void cwt_prep(const float* __restrict__ x,
                                                 __half* __restrict__ xT,
                                                 __half* __restrict__ W) {
    __shared__ double ps[1024];
    __shared__ double sc[1024];
    __shared__ float  k32[1024];
    __shared__ float  tile4[4][64 * 65];
    const int tid = threadIdx.x;

    if (blockIdx.x == 0) {
        uint4* W4 = (uint4*)W;
        const uint4 z = make_uint4(0u, 0u, 0u, 0u);
        for (int i = tid; i < WTOT_U4; i += 1024) W4[i] = z;

        const double delta = 16.0 / 1023.0;
        double t = (tid == 1023) ? 8.0 : (-8.0 + delta * (double)tid);
        ps[tid] = exp(-0.5 * t * t) * cos(5.0 * t);
        __syncthreads();

        double* a = ps; double* b = sc;
        for (int off = 1; off < 1024; off <<= 1) {
            double v = a[tid];
            if (tid >= off) v += a[tid - off];
            b[tid] = v;
            __syncthreads();
            double* tmp = a; a = b; b = tmp;
        }
        const double step = ((-8.0 + delta) + 8.0);   // NOT exactly 16/1023
        k32[tid] = (float)(a[tid] * step);
        __syncthreads();

        constexpr int SCe[5]   = {336, 167, 76, 27, 1};
        constexpr int KS2[5]   = {5408, 2720, 1248, 480, 64};
        constexpr int WOFFe[5] = {0, 86528, 130048, 150016, 157696};
        constexpr int CLOe[5]  = {0, 42, 65, 77, 83};
        for (int sl = 0; sl < 5; ++sl) {
            const int s = SCe[sl];
            const int L = 16 * s + 1;
            const double c = (double)s * step;
            const float sq = (float)sqrt((double)s);
            const int posoff = PADL2 - 8 * s - 1;
            const int kb0 = posoff - 32 * CLOe[sl];
            __half* wb = W + WOFFe[sl];
            const int Ks = KS2[sl];
            for (int i = tid; i <= L; i += 1024) {
                float g; bool wr = true;
                if (i == 0) {
                    g = sq * k32[0];
                } else if (i == L) {
                    long long jl = (long long)((double)(L - 1) / c);
                    if (jl > 1023) jl = 1023;
                    g = -sq * k32[jl];
                } else {
                    long long j1 = (long long)((double)i / c);
                    long long j0 = (long long)((double)(i - 1) / c);
                    if (j1 > 1023) j1 = 1023;
                    if (j0 > 1023) j0 = 1023;
                    wr = (j1 > j0);
                    g = sq * (k32[j1] - k32[j0]);
                }
                if (wr) {
                    const __half hg = __float2half(g);
                    const int kb = kb0 + i;
                    #pragma unroll
                    for (int bb = 0; bb < 16; ++bb)
                        wb[bb * Ks + kb + bb] = hg;
                }
            }
        }
    } else {
        const int g    = tid >> 8;                // 0..3: tile within block
        const int t256 = tid & 255;
        const int ti   = (blockIdx.x - 1) * 4 + g;  // 0..511
        const int n    = ti >> 5;
        const int t0   = (ti & 31) << 6;
        float* tl = tile4[g];

        const float4* src = (const float4*)(x + ((size_t)(n * T + t0)) * NC);
        #pragma unroll
        for (int k = 0; k < 4; ++k) {
            float4 v = src[t256 + 256 * k];
            const int flat = (t256 + 256 * k) * 4;
            const int tt = flat >> 6, c = flat & 63;
            tl[tt * 65 + c + 0] = v.x;
            tl[tt * 65 + c + 1] = v.y;
            tl[tt * 65 + c + 2] = v.z;
            tl[tt * 65 + c + 3] = v.w;
        }
        __syncthreads();
        const int lane = t256 & 63, w4 = t256 >> 6;
        for (int cc = w4; cc < 64; cc += 4) {
            xT[((size_t)(n * 64 + cc)) * T + t0 + lane] = __float2half(tl[lane * 65 + cc]);
        }
    }
}

// ---------------- kernel 2: Toeplitz-block MFMA conv, software-pipelined ----------------
// Out_sl[16A+b] = sum_k W_sl[b][k-32*CLO] * xsh[16A+k].
// Block = 1 row, 2 waves x N=64 cols (4 B-tiles). Depth-D modulo pipeline over
// chunks: slots hold A-frags (global W, L2-resident) and B-frags (LDS signal);
// loads for chunk c+D issue a full group of compute ahead of use. Unclamped
// prefetch reads <= +5 chunks past segment end: stays inside W / xsh (safe,
// values discarded).
template<int N, int DEPTH>
__device__ __forceinline__ void conv_seg(int c0, int c1,
                                         const _Float16* __restrict__ xb,
                                         const _Float16* const (&ap)[5],
                                         f32x4 (&acc)[5][4]) {
    half8 A[DEPTH][N];
    half8 B[DEPTH][4];
    #pragma unroll
    for (int d = 0; d < DEPTH; ++d) {
        const int ko = (c0 + d) << 5;
        #pragma unroll
        for (int sl = 0; sl < N; ++sl) A[d][sl] = *(const half8*)(ap[sl] + ko);
        #pragma unroll
        for (int j = 0; j < 4; ++j)   B[d][j]  = *(const half8*)(xb + 256 * j + ko);
    }
    int c = c0;
    for (; c + DEPTH <= c1; c += DEPTH) {
        #pragma unroll
        for (int d = 0; d < DEPTH; ++d) {
            #pragma unroll
            for (int sl = 0; sl < N; ++sl) {
                acc[sl][0] = __builtin_amdgcn_mfma_f32_16x16x32_f16(A[d][sl], B[d][0], acc[sl][0], 0, 0, 0);
                acc[sl][1] = __builtin_amdgcn_mfma_f32_16x16x32_f16(A[d][sl], B[d][1], acc[sl][1], 0, 0, 0);
                acc[sl][2] = __builtin_amdgcn_mfma_f32_16x16x32_f16(A[d][sl], B[d][2], acc[sl][2], 0, 0, 0);
                acc[sl][3] = __builtin_amdgcn_mfma_f32_16x16x32_f16(A[d][sl], B[d][3], acc[sl][3], 0, 0, 0);
            }
            const int ko = (c + DEPTH + d) << 5;   // prefetch (unclamped, memory-safe)
            #pragma unroll
            for (int sl = 0; sl < N; ++sl) A[d][sl] = *(const half8*)(ap[sl] + ko);
            #pragma unroll
            for (int j = 0; j < 4; ++j)   B[d][j]  = *(const half8*)(xb + 256 * j + ko);
        }
    }
    // tail: r = c1-c in [0, DEPTH); slots d<r hold valid chunks c+d
    #pragma unroll
    for (int d = 0; d < DEPTH; ++d) {
        if (d < c1 - c) {
            #pragma unroll
            for (int sl = 0; sl < N; ++sl) {
                acc[sl][0] = __builtin_amdgcn_mfma_f32_16x16x32_f16(A[d][sl], B[d][0], acc[sl][0], 0, 0, 0);
                acc[sl][1] = __builtin_amdgcn_mfma_f32_16x16x32_f16(A[d][sl], B[d][1], acc[sl][1], 0, 0, 0);
                acc[sl][2] = __builtin_amdgcn_mfma_f32_16x16x32_f16(A[d][sl], B[d][2], acc[sl][2], 0, 0, 0);
                acc[sl][3] = __builtin_amdgcn_mfma_f32_16x16x32_f16(A[d][sl], B[d][3], acc[sl][3], 0, 0, 0);
            }
        }
    }
}

__global__ __launch_bounds__(128, 2) void cwt_conv_mfma(const __half* __restrict__ xT,
                                                        const __half* __restrict__ Wg,
                                                        __half* __restrict__ outT) {
    constexpr int KS2[5]   = {5408, 2720, 1248, 480, 64};
    constexpr int WOFFe[5] = {0, 86528, 130048, 150016, 157696};
    constexpr int CLOe[5]  = {0, 42, 65, 77, 83};
    constexpr int OS[5]    = {4, 3, 2, 1, 0};

    __shared__ _Float16 xsh[XSH_N];               // 14880 B
    __shared__ _Float16 ostage[2048];             // 4096 B (1024/wave)
    const int tid  = threadIdx.x;
    const int row  = blockIdx.x;
    const int nidx = row >> 6;                    // batch n
    const int cidx = row & 63;                    // channel c
    const int lane = tid & 63;
    const int w    = tid >> 6;                    // wave 0/1: A-cols [64w, 64w+64)
    const int mcol = lane & 15;                   // A-frag: W row b;  B-frag: col n
    const int grp  = lane >> 4;                   // k-subgroup

    // ---- stage padded signal row (fp16) ----
    {
        uint4* x4 = (uint4*)xsh;
        const uint4 z = make_uint4(0u, 0u, 0u, 0u);
        for (int i = tid; i < XSH_N / 8; i += 128)
            if (i < PADL2 / 8 || i >= (PADL2 + T) / 8) x4[i] = z;
        const uint4* src = (const uint4*)(xT + (size_t)row * T);
        x4[PADL2 / 8 + tid] = src[tid];
        x4[PADL2 / 8 + 128 + tid] = src[128 + tid];
    }
    __syncthreads();

    // per-lane operand bases
    const _Float16* xb = xsh + 1024 * w + 16 * mcol + 8 * grp;  // tiles at +0,+256,+512,+768
    const _Float16* ap[5];
    #pragma unroll
    for (int sl = 0; sl < 5; ++sl)
        ap[sl] = (const _Float16*)Wg + WOFFe[sl] + mcol * KS2[sl] + 8 * grp
                 - (CLOe[sl] << 5);

    f32x4 acc[5][4];
    #pragma unroll
    for (int sl = 0; sl < 5; ++sl)
        #pragma unroll
        for (int j = 0; j < 4; ++j)
            acc[sl][j] = (f32x4){0.f, 0.f, 0.f, 0.f};

    // constant-alive-count segments over the unified chunk axis
    // alive: 336:[0,169) 167:[42,127) 76:[65,104) 27:[77,92) 1:[83,85)
    conv_seg<1,3>(  0,  42, xb, ap, acc);
    conv_seg<2,3>( 42,  65, xb, ap, acc);
    conv_seg<3,2>( 65,  77, xb, ap, acc);
    conv_seg<4,2>( 77,  83, xb, ap, acc);
    conv_seg<5,2>( 83,  85, xb, ap, acc);
    conv_seg<4,2>( 85,  92, xb, ap, acc);
    conv_seg<3,2>( 92, 104, xb, ap, acc);
    conv_seg<2,3>(104, 127, xb, ap, acc);
    conv_seg<1,3>(127, 169, xb, ap, acc);

    // ---- epilogue: D col=lane&15 -> A-col n, row=grp*4+r -> b; t' = 256j+16n+b ----
    // outT2 layout [n][tb][c][s][16]: lane l owns tb-local = l (t' = 16l+tt).
    _Float16* os = ostage + 1024 * w;             // wave-local, no barrier needed
    #pragma unroll
    for (int sl = 0; sl < 5; ++sl) {
        #pragma unroll
        for (int j = 0; j < 4; ++j) {
            half4v h;
            #pragma unroll
            for (int r = 0; r < 4; ++r) h[r] = (_Float16)acc[sl][j][r];
            *(half4v*)(os + 256 * j + 16 * mcol + 4 * grp) = h;
        }
        half8 o0 = *(const half8*)(os + 16 * lane);
        half8 o1 = *(const half8*)(os + 16 * lane + 8);
        __half* ob = outT + ((size_t)(((nidx * 128 + 64 * w + lane) * 64 + cidx) * 5 + OS[sl])) * 16;
        *(half8*)(ob)     = o0;
        *(half8*)(ob + 8) = o1;
    }
}

// ---------------- kernel 3: outT2[n][tb][c][s][16] -> out[n][t][c][s] ----------------
// Read side now fully contiguous (10 KB per block); LDS transposes [c][s][tt]->[tt][c][s].
__global__ __launch_bounds__(256) void cwt_fix(const __half* __restrict__ outT,
                                               float* __restrict__ out) {
    __shared__ float tile[16 * 320];              // [tt][c*5+s]
    const int b  = blockIdx.x;                    // 0..2047
    const int n  = b >> 7;
    const int tb = b & 127;
    const int tid = threadIdx.x;

    const uint4* src = (const uint4*)(outT + (size_t)(n * 128 + tb) * 5120);
    for (int i = tid; i < 640; i += 256) {
        uint4 v = src[i];                         // 8 halves: (c,s) fixed, tt0..tt0+7
        const __half* h = (const __half*)&v;
        const int h0  = i * 8;
        const int sg  = h0 >> 4;                  // c*5+s  (h0/16; tt in low 4 bits)
        const int tt0 = h0 & 15;                  // 0 or 8
        #pragma unroll
        for (int k = 0; k < 8; ++k) tile[(tt0 + k) * 320 + sg] = __half2float(h[k]);
    }
    __syncthreads();
    float4* dst = (float4*)(out + (size_t)(n * 2048 + tb * 16) * 320);
    const float4* tl = (const float4*)tile;
    for (int k = tid; k < 1280; k += 256) dst[k] = tl[k];
}

// ---------------- launch ----------------
extern "C" void kernel_launch(void* const* d_in, const int* in_sizes, int n_in,
                              void* d_out, int out_size, void* d_ws, size_t ws_size,
                              hipStream_t stream) {
    const float* x = (const float*)d_in[0];
    float* out = (float*)d_out;
    char* ws = (char*)d_ws;

    __half* W    = (__half*)ws;
    __half* xT   = (__half*)(ws + WS_XT);
    __half* outT = (__half*)(ws + WS_OUTT);

    cwt_prep<<<129, 1024, 0, stream>>>(x, xT, W);
    cwt_conv_mfma<<<NROWS, 128, 0, stream>>>(xT, W, outT);
    cwt_fix<<<2048, 256, 0, stream>>>(outT, out);
}